// Round 1
// baseline (36.105 us; speedup 1.0000x reference)
//
#include <hip/hip_runtime.h>

// Rydberg Hamiltonian apply: out[k] = diag(k)*state[k] + sum_b c_b * state[k ^ (1<<b)]
// N_QUBITS=22, DIM=2^22. Element-index bit b <-> qubit (21-b). c_b = 0.5*rabi[21-b].
// diag(k) = sum_i bits_i * (-detune_i) + sum_{i<j} U_ij bits_i bits_j
// Split k = hi(11 bits 11..21) | lo(11 bits 0..10):
//   diag = dhi[hi] + dlo[lo] + sum_{j set in lo} C[hi][j]
// where C[h][j] = sum_{i set in h} U(qubit(hi bit i), qubit(lo bit j)).

#define NQ 22
#define DIM (1u << NQ)            // 4194304
#define TILE_ELEMS 8192u          // bits 0..12 in LDS
#define TILE_F4 2048u
#define THREADS 512
#define CHUNKS 4
#define NBLOCKS (DIM / TILE_ELEMS) // 512

__device__ __align__(16) float g_dlo[2048];
__device__ __align__(16) float g_dhi[2048];
__device__ float g_C[2048 * 11];

__device__ __forceinline__ int uidx(int i, int j) {
    // np.triu_indices(22, k=1) row-major flatten, i<j
    return i * (43 - i) / 2 + (j - i - 1);
}

__global__ void build_tables_kernel(const float* __restrict__ detune,
                                    const float* __restrict__ U) {
    int h = blockIdx.x * blockDim.x + threadIdx.x;
    if (h >= 2048) return;
    // dlo: lo bit j (element bit j) <-> qubit 21-j
    float s = 0.f;
    for (int j = 0; j < 11; ++j)
        if ((h >> j) & 1) s -= detune[21 - j];
    for (int j2 = 1; j2 < 11; ++j2)
        for (int j1 = 0; j1 < j2; ++j1)
            if (((h >> j1) & 1) && ((h >> j2) & 1))
                s += U[uidx(21 - j2, 21 - j1)];   // qubit(21-j2) < qubit(21-j1)
    g_dlo[h] = s;
    // dhi: hi bit j (element bit 11+j) <-> qubit 10-j
    float s2 = 0.f;
    for (int j = 0; j < 11; ++j)
        if ((h >> j) & 1) s2 -= detune[10 - j];
    for (int j2 = 1; j2 < 11; ++j2)
        for (int j1 = 0; j1 < j2; ++j1)
            if (((h >> j1) & 1) && ((h >> j2) & 1))
                s2 += U[uidx(10 - j2, 10 - j1)];
    g_dhi[h] = s2;
    // C[h][j]: hi qubit (10-jh) in 0..10 always < lo qubit (21-j) in 11..21
    for (int j = 0; j < 11; ++j) {
        float c = 0.f;
        for (int jh = 0; jh < 11; ++jh)
            if ((h >> jh) & 1) c += U[uidx(10 - jh, 21 - j)];
        g_C[h * 11 + j] = c;
    }
}

__global__ __launch_bounds__(THREADS, 4) void ryd_main_kernel(
        const float* __restrict__ state, const float* __restrict__ rabi,
        float* __restrict__ out) {
    __shared__ float4 tileS[TILE_F4];   // 32 KB
    __shared__ float4 dloS[512];        // 8 KB
    const float4* __restrict__ stateF4 = (const float4*)state;
    float4* __restrict__ outF4 = (float4*)out;
    const unsigned t = threadIdx.x;
    const unsigned tb = blockIdx.x;
    const unsigned baseF4 = tb * TILE_F4;

    dloS[t] = ((const float4*)g_dlo)[t];
#pragma unroll
    for (int c = 0; c < CHUNKS; ++c) {
        unsigned f = t + 512u * (unsigned)c;
        tileS[f] = stateF4[baseF4 + f];
    }
    __syncthreads();

    const unsigned tileHi = tb * 4u;    // hi = element_index >> 11
#pragma unroll
    for (int c = 0; c < CHUNKS; ++c) {
        const unsigned f = t + 512u * (unsigned)c;   // f>>9 == c
        const unsigned hi = tileHi + (unsigned)c;    // wave-uniform -> s_loads
        float cj[11];
#pragma unroll
        for (int j = 0; j < 11; ++j) cj[j] = g_C[hi * 11 + j];
        float s = g_dhi[hi];
        const unsigned m = f & 511u;                 // lo bits 2..10
#pragma unroll
        for (int j = 0; j < 9; ++j)
            s += ((m >> j) & 1u) ? cj[j + 2] : 0.0f;
        const float4 dl = dloS[m];
        const float4 v = tileS[f];
        const float d0 = s + dl.x;
        const float d1 = s + cj[0] + dl.y;
        const float d2 = s + cj[1] + dl.z;
        const float d3 = s + cj[0] + cj[1] + dl.w;
        float4 acc;
        acc.x = d0 * v.x; acc.y = d1 * v.y; acc.z = d2 * v.z; acc.w = d3 * v.w;
        // bit 0 (qubit 21): swap within float pairs
        const float r0 = 0.5f * rabi[21];
        acc.x += r0 * v.y; acc.y += r0 * v.x; acc.z += r0 * v.w; acc.w += r0 * v.z;
        // bit 1 (qubit 20): swap halves of the float4
        const float r1 = 0.5f * rabi[20];
        acc.x += r1 * v.z; acc.y += r1 * v.w; acc.z += r1 * v.x; acc.w += r1 * v.y;
        // bits 2..12: partner float4 in LDS
#pragma unroll
        for (int b = 2; b <= 12; ++b) {
            const float rb = 0.5f * rabi[21 - b];
            const float4 p = tileS[f ^ (1u << (b - 2))];
            acc.x += rb * p.x; acc.y += rb * p.y; acc.z += rb * p.z; acc.w += rb * p.w;
        }
        // bits 13..21: partner float4 in global (L2/L3-resident)
        const unsigned F = baseF4 + f;
#pragma unroll
        for (int b = 13; b <= 21; ++b) {
            const float rb = 0.5f * rabi[21 - b];
            const float4 p = stateF4[F ^ (1u << (b - 2))];
            acc.x += rb * p.x; acc.y += rb * p.y; acc.z += rb * p.z; acc.w += rb * p.w;
        }
        outF4[F] = acc;
    }
}

extern "C" void kernel_launch(void* const* d_in, const int* in_sizes, int n_in,
                              void* d_out, int out_size, void* d_ws, size_t ws_size,
                              hipStream_t stream) {
    const float* state  = (const float*)d_in[0];
    const float* rabi   = (const float*)d_in[1];
    const float* detune = (const float*)d_in[2];
    const float* U      = (const float*)d_in[3];
    float* out = (float*)d_out;
    (void)in_sizes; (void)n_in; (void)out_size; (void)d_ws; (void)ws_size;

    hipLaunchKernelGGL(build_tables_kernel, dim3(8), dim3(256), 0, stream, detune, U);
    hipLaunchKernelGGL(ryd_main_kernel, dim3(NBLOCKS), dim3(THREADS), 0, stream,
                       state, rabi, out);
}

// Round 2
// 35.155 us; speedup vs baseline: 1.0270x; 1.0270x over previous
//
#include <hip/hip_runtime.h>

// Rydberg Hamiltonian apply: out[k] = diag(k)*state[k] + sum_b c_b * state[k ^ (1<<b)]
// N_QUBITS=22, DIM=2^22. Element-index bit b <-> qubit (21-b). c_b = 0.5*rabi[21-b].
// Two-pass butterfly split so ALL 22 bit-flips are served from LDS:
//   Pass "hi" (first):  out  = sum_{b=13..21} c_b * state[k^2^b]   (9 bits, LDS-local)
//   Pass "lo" (second): out += diag(k)*state[k] + sum_{b=0..12} c_b*state[k^2^b]
// Global traffic: 16+16 (hi) + 16+16+16 (lo) = 80 MB total.

#define NQ 22
#define DIM (1u << NQ)            // 4194304
#define TILE_ELEMS 8192u          // lo pass: bits 0..12 in LDS
#define TILE_F4 2048u
#define THREADS 512
#define CHUNKS 4
#define NBLOCKS (DIM / TILE_ELEMS) // 512

__device__ __align__(16) float g_dlo[2048];
__device__ __align__(16) float g_dhi[2048];
__device__ float g_C[2048 * 11];

__device__ __forceinline__ int uidx(int i, int j) {
    // np.triu_indices(22, k=1) row-major flatten, i<j
    return i * (43 - i) / 2 + (j - i - 1);
}

__global__ void build_tables_kernel(const float* __restrict__ detune,
                                    const float* __restrict__ U) {
    int h = blockIdx.x * blockDim.x + threadIdx.x;
    if (h >= 2048) return;
    // dlo: lo bit j (element bit j) <-> qubit 21-j
    float s = 0.f;
    for (int j = 0; j < 11; ++j)
        if ((h >> j) & 1) s -= detune[21 - j];
    for (int j2 = 1; j2 < 11; ++j2)
        for (int j1 = 0; j1 < j2; ++j1)
            if (((h >> j1) & 1) && ((h >> j2) & 1))
                s += U[uidx(21 - j2, 21 - j1)];
    g_dlo[h] = s;
    // dhi: hi bit j (element bit 11+j) <-> qubit 10-j
    float s2 = 0.f;
    for (int j = 0; j < 11; ++j)
        if ((h >> j) & 1) s2 -= detune[10 - j];
    for (int j2 = 1; j2 < 11; ++j2)
        for (int j1 = 0; j1 < j2; ++j1)
            if (((h >> j1) & 1) && ((h >> j2) & 1))
                s2 += U[uidx(10 - j2, 10 - j1)];
    g_dhi[h] = s2;
    // C[h][j]: hi qubit (10-jh) always < lo qubit (21-j)
    for (int j = 0; j < 11; ++j) {
        float c = 0.f;
        for (int jh = 0; jh < 11; ++jh)
            if ((h >> jh) & 1) c += U[uidx(10 - jh, 21 - j)];
        g_C[h * 11 + j] = c;
    }
}

// ---------------- Pass "hi": bits 13..21 (hi = element bits 13..21, 9 bits) ----------------
// Block: all 512 hi values x 4 consecutive float4 of lo. LDS 32 KB, 512 blocks.
#define P2_J4 4u
__global__ __launch_bounds__(512, 4) void ryd_hi_kernel(
        const float* __restrict__ state, const float* __restrict__ rabi,
        float* __restrict__ out) {
    __shared__ float4 tile[512 * P2_J4];   // 32 KB: tile[hi*4 + j4]
    const float4* __restrict__ sF4 = (const float4*)state;
    float4* __restrict__ oF4 = (float4*)out;
    const unsigned t = threadIdx.x;
    const unsigned j4 = t & 3u;
    const unsigned hi0 = t >> 2;           // [0,128)
    const unsigned baseJ4 = blockIdx.x * P2_J4;   // lo-f4 base (2048 total / 4)

    float cb[9];
#pragma unroll
    for (int b = 0; b < 9; ++b) cb[b] = 0.5f * rabi[8 - b];  // elem bit 13+b <-> qubit 8-b

#pragma unroll
    for (int m = 0; m < 4; ++m) {
        const unsigned hi = hi0 + 128u * (unsigned)m;
        tile[hi * 4u + j4] = sF4[hi * 2048u + baseJ4 + j4];
    }
    __syncthreads();
#pragma unroll
    for (int m = 0; m < 4; ++m) {
        const unsigned hi = hi0 + 128u * (unsigned)m;
        float4 acc = {0.f, 0.f, 0.f, 0.f};
#pragma unroll
        for (int b = 0; b < 9; ++b) {
            const float4 p = tile[(hi ^ (1u << b)) * 4u + j4];
            acc.x += cb[b] * p.x; acc.y += cb[b] * p.y;
            acc.z += cb[b] * p.z; acc.w += cb[b] * p.w;
        }
        oF4[hi * 2048u + baseJ4 + j4] = acc;
    }
}

// ---------------- Pass "lo": bits 0..12 + diagonal, accumulates onto out ----------------
__global__ __launch_bounds__(THREADS, 4) void ryd_lo_kernel(
        const float* __restrict__ state, const float* __restrict__ rabi,
        float* __restrict__ out) {
    __shared__ float4 tileS[TILE_F4];   // 32 KB
    __shared__ float4 dloS[512];        // 8 KB
    const float4* __restrict__ stateF4 = (const float4*)state;
    float4* __restrict__ outF4 = (float4*)out;
    const unsigned t = threadIdx.x;
    const unsigned tb = blockIdx.x;
    const unsigned baseF4 = tb * TILE_F4;

    dloS[t] = ((const float4*)g_dlo)[t];
    float4 vreg[CHUNKS];
#pragma unroll
    for (int c = 0; c < CHUNKS; ++c) {
        unsigned f = t + 512u * (unsigned)c;
        vreg[c] = stateF4[baseF4 + f];
        tileS[f] = vreg[c];
    }
    __syncthreads();

    const unsigned tileHi = tb * 4u;    // diag hi = element_index >> 11
#pragma unroll
    for (int c = 0; c < CHUNKS; ++c) {
        const unsigned f = t + 512u * (unsigned)c;   // f>>9 == c
        const unsigned F = baseF4 + f;
        const float4 prev = outF4[F];                // pass-hi partial (issue early)
        const unsigned hi = tileHi + (unsigned)c;    // wave-uniform -> s_loads
        float cj[11];
#pragma unroll
        for (int j = 0; j < 11; ++j) cj[j] = g_C[hi * 11 + j];
        float s = g_dhi[hi];
        const unsigned m = f & 511u;                 // lo bits 2..10
#pragma unroll
        for (int j = 0; j < 9; ++j)
            s += ((m >> j) & 1u) ? cj[j + 2] : 0.0f;
        const float4 dl = dloS[m];
        const float4 v = vreg[c];
        const float d0 = s + dl.x;
        const float d1 = s + cj[0] + dl.y;
        const float d2 = s + cj[1] + dl.z;
        const float d3 = s + cj[0] + cj[1] + dl.w;
        float4 acc;
        acc.x = d0 * v.x; acc.y = d1 * v.y; acc.z = d2 * v.z; acc.w = d3 * v.w;
        // bit 0 (qubit 21): swap within float pairs
        const float r0 = 0.5f * rabi[21];
        acc.x += r0 * v.y; acc.y += r0 * v.x; acc.z += r0 * v.w; acc.w += r0 * v.z;
        // bit 1 (qubit 20): swap halves of the float4
        const float r1 = 0.5f * rabi[20];
        acc.x += r1 * v.z; acc.y += r1 * v.w; acc.z += r1 * v.x; acc.w += r1 * v.y;
        // bits 2..12: partner float4 in LDS
#pragma unroll
        for (int b = 2; b <= 12; ++b) {
            const float rb = 0.5f * rabi[21 - b];
            const float4 p = tileS[f ^ (1u << (b - 2))];
            acc.x += rb * p.x; acc.y += rb * p.y; acc.z += rb * p.z; acc.w += rb * p.w;
        }
        acc.x += prev.x; acc.y += prev.y; acc.z += prev.z; acc.w += prev.w;
        outF4[F] = acc;
    }
}

extern "C" void kernel_launch(void* const* d_in, const int* in_sizes, int n_in,
                              void* d_out, int out_size, void* d_ws, size_t ws_size,
                              hipStream_t stream) {
    const float* state  = (const float*)d_in[0];
    const float* rabi   = (const float*)d_in[1];
    const float* detune = (const float*)d_in[2];
    const float* U      = (const float*)d_in[3];
    float* out = (float*)d_out;
    (void)in_sizes; (void)n_in; (void)out_size; (void)d_ws; (void)ws_size;

    hipLaunchKernelGGL(build_tables_kernel, dim3(8), dim3(256), 0, stream, detune, U);
    hipLaunchKernelGGL(ryd_hi_kernel, dim3(512), dim3(512), 0, stream, state, rabi, out);
    hipLaunchKernelGGL(ryd_lo_kernel, dim3(NBLOCKS), dim3(THREADS), 0, stream,
                       state, rabi, out);
}